// Round 6
// baseline (2983.825 us; speedup 1.0000x reference)
//
#include <hip/hip_runtime.h>
#include <math.h>

// ---------------- problem constants ----------------
constexpr int BB   = 4;
constexpr int TT   = 400;
constexpr int FF   = 1025;
constexpr int NFFT = 2048;
constexpr int HOP  = 512;
constexpr int PADD = 1024;
constexpr int LL   = HOP * (TT - 1);        // 204288
constexpr int LPAD = NFFT + HOP * (TT - 1); // 206336
constexpr int NITER = 60;
constexpr double MOM = 0.99 / 1.99;
constexpr double EPSV = 1e-16;
constexpr double DPI = 3.14159265358979323846;

// workspace offsets in DOUBLES (all even -> 16B alignment)
constexpr size_t OFF_TW1024 = 0;          // 1024 double2 = 2048 d
constexpr size_t OFF_TW2048 = 2048;       // 1025 double2 = 2050 d
constexpr size_t OFF_ANG    = 4098;       // B*T*F double2 = 3280000 d
constexpr size_t OFF_TPR    = 3284098;    // 3280000 d
constexpr size_t OFF_FRM    = 6564098;    // B*T*2048 = 3276800 d
constexpr size_t OFF_XP     = 9840898;    // B*LPAD = 825344 d
constexpr size_t OFF_WIN32  = 10666242;   // f32 window: 2048 f = 1024 d
constexpr size_t OFF_WSQ32  = 10667266;   // f32 wsq divisor: 206336 f = 103168 d
constexpr size_t WS_DOUBLES = 10770434;   // ~86.2 MB

__device__ __forceinline__ double2 cmuld(double2 a, double2 b) {
    return make_double2(a.x * b.x - a.y * b.y, a.x * b.y + a.y * b.x);
}

// ---------------- numpy SIMD float32 cosine, bit-exact replica ----------------
// Mirrors numpy/_core/src/umath/loops_trigonometric.dispatch (SIMD path,
// |x| < 117435.992f): quadrant via rint(x*2/pi) using the 1.5*2^23 trick,
// 4-constant Cody-Waite FMA range reduction, tuned sin/cos polynomials on
// [-pi/4, pi/4], cos(x) computed as sin-shifted (quadrant + 1).
__device__ __forceinline__ float np_cosf(float x) {
    const float rint_cvt = 0x1.800000p+23f;  // 12582912.0f
    float qf = __builtin_fmaf(x, 0x1.45f306p-1f, rint_cvt) - rint_cvt;
    // Cody-Waite range reduction (FMA chain)
    float r = __builtin_fmaf(qf, -0x1.921fb0p+0f, x);
    r = __builtin_fmaf(qf, -0x1.5110b4p-22f, r);
    r = __builtin_fmaf(qf, -0x1.846988p-48f, r);
    r = __builtin_fmaf(qf, -0x1.8cc966p-73f, r);
    int q = (int)qf + 1;  // cos(x) = sin(x + pi/2)
    float r2 = r * r;
    // cosine poly (max 0.875 ulp on [-pi/4, pi/4])
    float cosp = __builtin_fmaf(0x1.98e616p-16f, r2, -0x1.6c06dcp-10f);
    cosp = __builtin_fmaf(cosp, r2, 0x1.55553cp-5f);
    cosp = __builtin_fmaf(cosp, r2, -0x1.000000p-1f);
    cosp = __builtin_fmaf(cosp, r2, 0x1.000000p+0f);
    // sine poly (max 0.647 ulp on [-pi/4, pi/4])
    float sinp = __builtin_fmaf(0x1.7d3bbcp-19f, r2, -0x1.a06bbap-13f);
    sinp = __builtin_fmaf(sinp, r2, 0x1.11119ap-7f);
    sinp = __builtin_fmaf(sinp, r2, -0x1.555548p-3f);
    sinp = sinp * r2;
    sinp = __builtin_fmaf(sinp, r, r);
    // blend on bit0 (odd -> cos poly), negate on bit1
    float res = (q & 1) ? cosp : sinp;
    return (q & 2) ? -res : res;
}

// ---------------- init kernels ----------------
// Window replicates numpy f32 semantics exactly:
//   w = f32(0.5 - f32(0.5 * np_cosf(f32(f32(f32(2pi)*i) / 2048))))
__global__ void k_init_tables(double2* tw1024, double2* tw2048, float* win) {
    int n = blockIdx.x * blockDim.x + threadIdx.x;
    if (n < 1024) {
        double th = -2.0 * DPI * (double)n / 1024.0;
        double s, c; sincos(th, &s, &c);
        tw1024[n] = make_double2(c, s);
    }
    if (n < 1025) {
        double th = -2.0 * DPI * (double)n / 2048.0;
        double s, c; sincos(th, &s, &c);
        tw2048[n] = make_double2(c, s);
    }
    if (n < 2048) {
        const float TWO_PI_F = 6.283185307179586f;  // rounds to f32(2*pi)
        float ang = __fdiv_rn(__fmul_rn(TWO_PI_F, (float)n), 2048.0f);
        float c = np_cosf(ang);
        win[n] = __fsub_rn(0.5f, __fmul_rn(0.5f, c));
    }
}

// wsq replicates numpy: float32 zeros, += f32(w*w) in ascending-t order,
// then where(wsq > 1e-11f, wsq, 1.0f). Stored as the final f32 divisor.
__global__ void k_init_wsq(const float* __restrict__ win, float* __restrict__ wsq) {
    int m = blockIdx.x * blockDim.x + threadIdx.x;
    if (m >= LPAD) return;
    int tlo = (m - (NFFT - HOP)) >> 9;
    if (tlo < 0) tlo = 0;
    int thi = m >> 9;
    if (thi > TT - 1) thi = TT - 1;
    float s = 0.0f;
    for (int t = tlo; t <= thi; ++t) {
        float w = win[m - (t << 9)];
        s = __fadd_rn(s, __fmul_rn(w, w));
    }
    wsq[m] = (s > 1e-11f) ? s : 1.0f;
}

__global__ void k_init_state(double2* __restrict__ ang, double2* __restrict__ tpr) {
    int i = blockIdx.x * blockDim.x + threadIdx.x;
    if (i < BB * TT * FF) {
        ang[i] = make_double2(1.0, 0.0);
        tpr[i] = make_double2(0.0, 0.0);
    }
}

// ---------------- 1024-pt radix-4 Stockham FFT in LDS (fp64) ----------------
// DIR=-1 forward (e^{-i}), DIR=+1 inverse (unnormalized). 256 threads.
// Caller must __syncthreads() after filling bufA. Result lands in bufB.
template <int DIR>
__device__ void fft1024(double2* bufA, double2* bufB, const double2* __restrict__ tw, int tid) {
    double2* src = bufA;
    double2* dst = bufB;
#pragma unroll
    for (int s = 0; s < 5; ++s) {
        const int p = 1 << (2 * s);
        int k = tid & (p - 1);
        int j = ((tid - k) << 2) + k;
        double2 a = src[tid];
        double2 b = src[tid + 256];
        double2 c = src[tid + 512];
        double2 d = src[tid + 768];
        int t1 = k << (8 - 2 * s);
        double2 w1 = tw[t1 & 1023];
        double2 w2 = tw[(2 * t1) & 1023];
        double2 w3 = tw[(3 * t1) & 1023];
        if (DIR > 0) { w1.y = -w1.y; w2.y = -w2.y; w3.y = -w3.y; }
        b = cmuld(b, w1);
        c = cmuld(c, w2);
        d = cmuld(d, w3);
        double2 u0 = make_double2(a.x + c.x, a.y + c.y);
        double2 u1 = make_double2(a.x - c.x, a.y - c.y);
        double2 v0 = make_double2(b.x + d.x, b.y + d.y);
        double2 v1 = make_double2(b.x - d.x, b.y - d.y);
        double2 o0 = make_double2(u0.x + v0.x, u0.y + v0.y);
        double2 o2 = make_double2(u0.x - v0.x, u0.y - v0.y);
        double2 o1, o3;
        if (DIR < 0) {
            o1 = make_double2(u1.x + v1.y, u1.y - v1.x);
            o3 = make_double2(u1.x - v1.y, u1.y + v1.x);
        } else {
            o1 = make_double2(u1.x - v1.y, u1.y + v1.x);
            o3 = make_double2(u1.x + v1.y, u1.y - v1.x);
        }
        dst[j] = o0;
        dst[j + p] = o1;
        dst[j + 2 * p] = o2;
        dst[j + 3 * p] = o3;
        __syncthreads();
        double2* tmp = src; src = dst; dst = tmp;
    }
}

// ---------------- kernel A: spec*angles -> irfft -> windowed frames ----------------
__global__ __launch_bounds__(256) void k_istft_frames(
    const float* __restrict__ mag, const double2* __restrict__ ang,
    const double2* __restrict__ tw1024, const double2* __restrict__ tw2048,
    const float* __restrict__ win, double* __restrict__ frames) {
    __shared__ double2 X[1025];
    __shared__ double2 ZB[1024];
    const int fid = blockIdx.x;
    const int tid = threadIdx.x;
    const float* mg = mag + (size_t)fid * FF;
    const double2* an = ang + (size_t)fid * FF;
#pragma unroll
    for (int q = 0; q < 4; ++q) {
        int k = tid + 256 * q;
        double m = (double)mg[k];
        double2 a = an[k];
        X[k] = make_double2(m * a.x, m * a.y);
    }
    if (tid == 0) {
        double m = (double)mg[1024];
        double2 a = an[1024];
        X[1024] = make_double2(m * a.x, m * a.y);
    }
    __syncthreads();
    // pre-twist: Z[k] = A + i*B, A=(X[k]+X*[M-k])/2, B=conj(w_k)*(X[k]-X*[M-k])/2
    // c2r semantics: imag of X[0] and X[1024] discarded.
#pragma unroll
    for (int q = 0; q < 4; ++q) {
        int k = tid + 256 * q;
        double2 Xk = X[k];
        double2 Xc = X[1024 - k];
        if (k == 0) { Xk.y = 0.0; Xc.y = 0.0; }
        Xc.y = -Xc.y;
        double2 A = make_double2(0.5 * (Xk.x + Xc.x), 0.5 * (Xk.y + Xc.y));
        double2 D = make_double2(0.5 * (Xk.x - Xc.x), 0.5 * (Xk.y - Xc.y));
        double2 w = tw2048[k];
        w.y = -w.y;  // conj -> e^{+2pi i k/2048}
        double2 Bv = cmuld(w, D);
        ZB[k] = make_double2(A.x - Bv.y, A.y + Bv.x);
    }
    __syncthreads();
    fft1024<1>(ZB, X, tw1024, tid);  // result in X[0..1023]
    double2* fr = reinterpret_cast<double2*>(frames + (size_t)fid * NFFT);
    const float2* w2 = reinterpret_cast<const float2*>(win);
#pragma unroll
    for (int q = 0; q < 4; ++q) {
        int m = tid + 256 * q;
        double2 z = X[m];
        float2 wv = w2[m];
        fr[m] = make_double2(z.x * (1.0 / 1024.0) * (double)wv.x,
                             z.y * (1.0 / 1024.0) * (double)wv.y);
    }
}

// ---------------- kernel B: overlap-add + normalize + reflect-pad ----------------
__global__ __launch_bounds__(256) void k_ola(
    const double* __restrict__ frames, const float* __restrict__ wsq,
    double* __restrict__ xp) {
    int gid = blockIdx.x * 256 + threadIdx.x;  // exactly B*LPAD threads
    int b = gid / LPAD;
    int p = gid - b * LPAD;
    int j = p - PADD;
    if (j < 0) j = -j;
    else if (j >= LL) j = 2 * LL - 2 - j;
    int m = j + PADD;
    int tlo = (m - (NFFT - HOP)) >> 9;
    if (tlo < 0) tlo = 0;
    int thi = m >> 9;
    if (thi > TT - 1) thi = TT - 1;
    const double* fb = frames + (size_t)b * TT * NFFT;
    double s = 0.0;
    for (int t = tlo; t <= thi; ++t) s += fb[(size_t)t * NFFT + (m - (t << 9))];
    xp[gid] = s / (double)wsq[m];
}

// ---------------- kernel C: stft + fused phase update ----------------
__global__ __launch_bounds__(256) void k_stft_update(
    const double* __restrict__ xp, const double2* __restrict__ tw1024,
    const double2* __restrict__ tw2048, const float* __restrict__ win,
    double2* __restrict__ ang, double2* __restrict__ tpr) {
    __shared__ double2 ZA[1024];
    __shared__ double2 ZBf[1024];
    const int fid = blockIdx.x;
    const int b = fid / TT;
    const int t = fid - b * TT;
    const int tid = threadIdx.x;
    const double2* xb = reinterpret_cast<const double2*>(xp + (size_t)b * LPAD + (size_t)t * HOP);
    const float2* w2 = reinterpret_cast<const float2*>(win);
#pragma unroll
    for (int q = 0; q < 4; ++q) {
        int k = tid + 256 * q;
        double2 v = xb[k];
        float2 wv = w2[k];
        ZA[k] = make_double2(v.x * (double)wv.x, v.y * (double)wv.y);
    }
    __syncthreads();
    fft1024<-1>(ZA, ZBf, tw1024, tid);  // result in ZBf
    size_t base = (size_t)fid * FF;
#pragma unroll
    for (int q = 0; q < 5; ++q) {
        int k = tid + 256 * q;
        if (k <= 1024) {
            double2 Zk = ZBf[k & 1023];
            double2 Zc = ZBf[(1024 - k) & 1023];
            Zc.y = -Zc.y;
            double2 A = make_double2(0.5 * (Zk.x + Zc.x), 0.5 * (Zk.y + Zc.y));
            double2 D = make_double2(Zk.x - Zc.x, Zk.y - Zc.y);
            double2 Bv = make_double2(0.5 * D.y, -0.5 * D.x);  // -i*D/2
            double2 w = tw2048[k];
            double2 wB = cmuld(w, Bv);
            double2 Xk = make_double2(A.x + wB.x, A.y + wB.y);
            double2 tp = tpr[base + k];
            double2 a = make_double2(Xk.x - MOM * tp.x, Xk.y - MOM * tp.y);
            double r = sqrt(a.x * a.x + a.y * a.y);
            double d = r + EPSV;
            ang[base + k] = make_double2(a.x / d, a.y / d);
            tpr[base + k] = Xk;
        }
    }
}

// ---------------- final: overlap-add -> trimmed fp32 output ----------------
__global__ __launch_bounds__(256) void k_ola_out(
    const double* __restrict__ frames, const float* __restrict__ wsq,
    float* __restrict__ out) {
    int gid = blockIdx.x * 256 + threadIdx.x;  // exactly B*L threads
    int b = gid / LL;
    int j = gid - b * LL;
    int m = j + PADD;
    int tlo = (m - (NFFT - HOP)) >> 9;
    if (tlo < 0) tlo = 0;
    int thi = m >> 9;
    if (thi > TT - 1) thi = TT - 1;
    const double* fb = frames + (size_t)b * TT * NFFT;
    double s = 0.0;
    for (int t = tlo; t <= thi; ++t) s += fb[(size_t)t * NFFT + (m - (t << 9))];
    out[gid] = (float)(s / (double)wsq[m]);
}

extern "C" void kernel_launch(void* const* d_in, const int* in_sizes, int n_in,
                              void* d_out, int out_size, void* d_ws, size_t ws_size,
                              hipStream_t stream) {
    if (ws_size < WS_DOUBLES * sizeof(double)) return;  // fail loudly if ws too small
    const float* mag = (const float*)d_in[0];  // (B,T,F) fp32
    double* ws = (double*)d_ws;
    double2* tw1024 = (double2*)(ws + OFF_TW1024);
    double2* tw2048 = (double2*)(ws + OFF_TW2048);
    double2* angv   = (double2*)(ws + OFF_ANG);
    double2* tprv   = (double2*)(ws + OFF_TPR);
    double* frames  = ws + OFF_FRM;
    double* xp      = ws + OFF_XP;
    float* win      = (float*)(ws + OFF_WIN32);
    float* wsq      = (float*)(ws + OFF_WSQ32);

    k_init_tables<<<8, 256, 0, stream>>>(tw1024, tw2048, win);
    k_init_wsq<<<LPAD / 256, 256, 0, stream>>>(win, wsq);
    k_init_state<<<(BB * TT * FF + 255) / 256, 256, 0, stream>>>(angv, tprv);

    for (int it = 0; it < NITER; ++it) {
        k_istft_frames<<<BB * TT, 256, 0, stream>>>(mag, angv, tw1024, tw2048, win, frames);
        k_ola<<<(BB * LPAD) / 256, 256, 0, stream>>>(frames, wsq, xp);
        k_stft_update<<<BB * TT, 256, 0, stream>>>(xp, tw1024, tw2048, win, angv, tprv);
    }
    k_istft_frames<<<BB * TT, 256, 0, stream>>>(mag, angv, tw1024, tw2048, win, frames);
    k_ola_out<<<(BB * LL) / 256, 256, 0, stream>>>(frames, wsq, (float*)d_out);
}